// Round 1
// baseline (1074.707 us; speedup 1.0000x reference)
//
#include <hip/hip_runtime.h>
#include <cstddef>

#define EPS_ 1e-5f

// Problem constants: B=32, C=256, L=4096, I=64
// x layout [B][C][L] row-major; elem (b,c,l) at (b*256+c)*4096 + l.

// ---- ws float offsets ----
// Folded weights: W1t[c][i] = s1[i]*w1[br][i][c]; W2t[i][c] = s2[c]*w2[br][c][i]
#define OFF_W1T0 0
#define OFF_W2T0 16384
#define OFF_W1T2 32768
#define OFF_W2T2 49152
#define OFF_C1_0 65536   // 64   c1 = bn1_b + s1*(b1 - bn1_m)
#define OFF_C2_0 65600   // 256
#define OFF_C1_2 65856   // 64
#define OFF_C2_2 65920   // 256
#define OFF_MEANAB 66176 // [32][256]
#define OFF_SUMABC 74368 // [32][256] (atomic accum, zeroed in prep)
#define OFF_G1 82560     // [32][256]
#define OFF_G3 90752     // [32][256]
#define OFF_XO1 131072   // [32][256][4096]
#define OFF_P 33685504   // [32][256][4096]  p = 0.5*(1-wei)*x_c
// total ws need: 67239936 floats = ~269 MB

// ============ prep: fold BN into weights, zero sum_abc ============
__global__ __launch_bounds__(256) void k_prep(
    const float* __restrict__ w1, const float* __restrict__ b1,
    const float* __restrict__ bn1g, const float* __restrict__ bn1b,
    const float* __restrict__ bn1m, const float* __restrict__ bn1v,
    const float* __restrict__ w2, const float* __restrict__ b2,
    const float* __restrict__ bn2g, const float* __restrict__ bn2b,
    const float* __restrict__ bn2m, const float* __restrict__ bn2v,
    float* __restrict__ ws)
{
  int idx = blockIdx.x * 256 + threadIdx.x;
  if (idx < 32768) {                       // W1t, branches 0 and 2
    int slot = idx >> 14, r = idx & 16383;
    int br = slot << 1;
    int c = r >> 6, i = r & 63;
    int gi = (br << 6) + i;
    float s1 = bn1g[gi] / sqrtf(bn1v[gi] + EPS_);
    ws[OFF_W1T0 + (slot << 15) + r] = w1[gi * 256 + c] * s1;
  } else if (idx < 65536) {                // W2t
    int j = idx - 32768;
    int slot = j >> 14, r = j & 16383;
    int br = slot << 1;
    int i = r >> 8, c = r & 255;
    int gc = (br << 8) + c;
    float s2 = bn2g[gc] / sqrtf(bn2v[gc] + EPS_);
    ws[OFF_W2T0 + (slot << 15) + r] = w2[gc * 64 + i] * s2;
  } else if (idx < 65664) {                // c1
    int j = idx - 65536;
    int slot = j >> 6, i = j & 63;
    int gi = ((slot << 1) << 6) + i;
    float s1 = bn1g[gi] / sqrtf(bn1v[gi] + EPS_);
    ws[OFF_C1_0 + slot * 320 + i] = bn1b[gi] + s1 * (b1[gi] - bn1m[gi]);
  } else if (idx < 66176) {                // c2
    int j = idx - 65664;
    int slot = j >> 8, c = j & 255;
    int gc = ((slot << 1) << 8) + c;
    float s2 = bn2g[gc] / sqrtf(bn2v[gc] + EPS_);
    ws[OFF_C2_0 + slot * 320 + c] = bn2b[gc] + s2 * (b2[gc] - bn2m[gc]);
  } else if (idx < 74368) {                // zero sum_abc
    ws[OFF_SUMABC + (idx - 66176)] = 0.0f;
  }
}

// ============ K1: mean over L of (x_a + x_b), one block per (b,c) ============
__global__ __launch_bounds__(256) void k_mean_ab(
    const float* __restrict__ xa, const float* __restrict__ xb,
    float* __restrict__ mean_ab)
{
  const int row = blockIdx.x;              // b*256 + c
  const size_t base4 = (size_t)row * 1024; // float4 units
  const float4* a4 = (const float4*)xa;
  const float4* b4 = (const float4*)xb;
  float s = 0.0f;
#pragma unroll
  for (int k = 0; k < 4; ++k) {
    float4 va = a4[base4 + k * 256 + threadIdx.x];
    float4 vb = b4[base4 + k * 256 + threadIdx.x];
    s += (va.x + vb.x) + (va.y + vb.y) + (va.z + vb.z) + (va.w + vb.w);
  }
#pragma unroll
  for (int m = 32; m; m >>= 1) s += __shfl_xor(s, m, 64);
  __shared__ float part[4];
  if ((threadIdx.x & 63) == 0) part[threadIdx.x >> 6] = s;
  __syncthreads();
  if (threadIdx.x == 0)
    mean_ab[row] = (part[0] + part[1] + part[2] + part[3]) * (1.0f / 4096.0f);
}

// ============ global-pool attention branch (br = 1 or 3), one block per b ===
__global__ __launch_bounds__(256) void k_gatt(
    int br, const float* __restrict__ vin, float scale,
    const float* __restrict__ w1, const float* __restrict__ b1,
    const float* __restrict__ bn1g, const float* __restrict__ bn1b,
    const float* __restrict__ bn1m, const float* __restrict__ bn1v,
    const float* __restrict__ w2, const float* __restrict__ b2,
    const float* __restrict__ bn2g, const float* __restrict__ bn2b,
    const float* __restrict__ bn2m, const float* __restrict__ bn2v,
    float* __restrict__ gout)
{
  const int b = blockIdx.x, tid = threadIdx.x;
  __shared__ float xs[256];
  __shared__ float as[64];
  xs[tid] = vin[(b << 8) + tid] * scale;
  __syncthreads();
  if (tid < 64) {
    const int gi = (br << 6) + tid;
    const float* wr = w1 + gi * 256;
    float acc = 0.0f;
#pragma unroll 8
    for (int c = 0; c < 256; ++c) acc = fmaf(wr[c], xs[c], acc);
    float s1 = bn1g[gi] / sqrtf(bn1v[gi] + EPS_);
    float h = s1 * (acc + b1[gi] - bn1m[gi]) + bn1b[gi];
    as[tid] = fmaxf(h, 0.0f);
  }
  __syncthreads();
  const int gc = (br << 8) + tid;
  const float* wr2 = w2 + gc * 64;
  float acc = 0.0f;
#pragma unroll 8
  for (int i = 0; i < 64; ++i) acc = fmaf(wr2[i], as[i], acc);
  float s2 = bn2g[gc] / sqrtf(bn2v[gc] + EPS_);
  gout[(b << 8) + tid] = s2 * (acc + b2[gc] - bn2m[gc]) + bn2b[gc];
}

// ============ K2: local attn branch 0 + first blend ============
// 4096 blocks x 128 threads; block = (b, 32-position l-tile).
// xs = x_a+x_b staged in LDS; W from global (L2-resident).
// Writes xo1, p = 0.5*(1-wei)*x_c; atomically accumulates sum over l of (xo1+x_c).
__global__ __launch_bounds__(128) void k_local1(
    const float* __restrict__ xa, const float* __restrict__ xb,
    const float* __restrict__ xc,
    const float* __restrict__ W1t, const float* __restrict__ W2t,
    const float* __restrict__ c1, const float* __restrict__ c2,
    const float* __restrict__ g1,
    float* __restrict__ xo1, float* __restrict__ pbuf,
    float* __restrict__ sumabc)
{
  const int tid = threadIdx.x;
  const int b = blockIdx.x >> 7;
  const int l0 = (blockIdx.x & 127) << 5;
  __shared__ float xs[256][36];   // padded rows, 16B aligned
  __shared__ float hsm[64][36];
  __shared__ float cgs[256];      // c2 + g1 row
  const size_t rowbase = ((size_t)b << 20) + (size_t)l0;

  { // stage xs = xa + xb (coalesced: 8 lanes x float4 per c-row)
    const int cw = tid >> 3, g = (tid & 7) << 2;
#pragma unroll
    for (int pass = 0; pass < 16; ++pass) {
      const int c = (pass << 4) + cw;
      const size_t off = rowbase + ((size_t)c << 12) + g;
      const float4 va = *(const float4*)(xa + off);
      const float4 vb = *(const float4*)(xb + off);
      float4 v;
      v.x = va.x + vb.x; v.y = va.y + vb.y; v.z = va.z + vb.z; v.w = va.w + vb.w;
      *(float4*)&xs[c][g] = v;
    }
    cgs[tid] = c2[tid] + g1[(b << 8) + tid];
    cgs[tid + 128] = c2[tid + 128] + g1[(b << 8) + tid + 128];
  }
  __syncthreads();

  { // layer 1: h[64][32], micro 4i x 4t
    const int ti = tid >> 3, tt4 = (tid & 7) << 2;
    float acc[4][4] = {};
    const float* wp = W1t + (ti << 2);
#pragma unroll 4
    for (int c = 0; c < 256; ++c) {
      const float4 wv = *(const float4*)(wp + (c << 6));
      const float4 xv = *(const float4*)&xs[c][tt4];
      const float wv4[4] = {wv.x, wv.y, wv.z, wv.w};
      const float xv4[4] = {xv.x, xv.y, xv.z, xv.w};
#pragma unroll
      for (int a = 0; a < 4; ++a)
#pragma unroll
        for (int j = 0; j < 4; ++j)
          acc[a][j] = fmaf(wv4[a], xv4[j], acc[a][j]);
    }
#pragma unroll
    for (int a = 0; a < 4; ++a) {
      const float cv = c1[(ti << 2) + a];
      float4 h;
      h.x = fmaxf(acc[a][0] + cv, 0.0f);
      h.y = fmaxf(acc[a][1] + cv, 0.0f);
      h.z = fmaxf(acc[a][2] + cv, 0.0f);
      h.w = fmaxf(acc[a][3] + cv, 0.0f);
      *(float4*)&hsm[(ti << 2) + a][tt4] = h;
    }
  }
  __syncthreads();

  { // layer 2 (micro 8c x 8t) + sigmoid + blend
    const int cg = tid >> 2, tg8 = (tid & 3) << 3;
    float acc2[8][8] = {};
#pragma unroll 2
    for (int i = 0; i < 64; ++i) {
      const float4 h0 = *(const float4*)&hsm[i][tg8];
      const float4 h1 = *(const float4*)&hsm[i][tg8 + 4];
      const float* w2p = W2t + (i << 8) + (cg << 3);
      const float4 w0 = *(const float4*)(w2p);
      const float4 w1v = *(const float4*)(w2p + 4);
      const float hh[8] = {h0.x, h0.y, h0.z, h0.w, h1.x, h1.y, h1.z, h1.w};
      const float ww[8] = {w0.x, w0.y, w0.z, w0.w, w1v.x, w1v.y, w1v.z, w1v.w};
#pragma unroll
      for (int a = 0; a < 8; ++a)
#pragma unroll
        for (int j = 0; j < 8; ++j)
          acc2[a][j] = fmaf(ww[a], hh[j], acc2[a][j]);
    }

#pragma unroll
    for (int a = 0; a < 8; ++a) {
      const int cc = (cg << 3) + a;
      const float cgv = cgs[cc];
      const size_t off = rowbase + ((size_t)cc << 12) + tg8;
      const float4 a0 = *(const float4*)(xa + off);
      const float4 a1 = *(const float4*)(xa + off + 4);
      const float4 q0 = *(const float4*)(xc + off);
      const float4 q1 = *(const float4*)(xc + off + 4);
      const float4 s0 = *(const float4*)&xs[cc][tg8];
      const float4 s1 = *(const float4*)&xs[cc][tg8 + 4];
      const float av[8] = {a0.x, a0.y, a0.z, a0.w, a1.x, a1.y, a1.z, a1.w};
      const float qv[8] = {q0.x, q0.y, q0.z, q0.w, q1.x, q1.y, q1.z, q1.w};
      const float sv[8] = {s0.x, s0.y, s0.z, s0.w, s1.x, s1.y, s1.z, s1.w};
      float ov[8], pv[8], sab = 0.0f;
#pragma unroll
      for (int j = 0; j < 8; ++j) {
        const float w = 1.0f / (1.0f + __expf(-(acc2[a][j] + cgv)));
        // xo1 = xa*w + xb*(1-w), with xb = sum - xa:
        const float xo = sv[j] * (1.0f - w) + av[j] * (2.0f * w - 1.0f);
        ov[j] = xo;
        pv[j] = 0.5f * (1.0f - w) * qv[j];
        sab += xo + qv[j];
      }
      float4 o0 = {ov[0], ov[1], ov[2], ov[3]}, o1 = {ov[4], ov[5], ov[6], ov[7]};
      float4 p0 = {pv[0], pv[1], pv[2], pv[3]}, p1 = {pv[4], pv[5], pv[6], pv[7]};
      *(float4*)(xo1 + off) = o0;  *(float4*)(xo1 + off + 4) = o1;
      *(float4*)(pbuf + off) = p0; *(float4*)(pbuf + off + 4) = p1;
      sab += __shfl_xor(sab, 1, 64);
      sab += __shfl_xor(sab, 2, 64);
      if ((tid & 3) == 0) atomicAdd(&sumabc[(b << 8) + cc], sab);
    }
  }
}

// ============ K4: local attn branch 2 + final combine ============
// out = 0.5*xo1*(1+wei2) + p, with xo1 = xs - xc (xs = xo1+xc staged).
__global__ __launch_bounds__(128) void k_local2(
    const float* __restrict__ xo1, const float* __restrict__ xc,
    const float* __restrict__ pbuf,
    const float* __restrict__ W1t, const float* __restrict__ W2t,
    const float* __restrict__ c1, const float* __restrict__ c2,
    const float* __restrict__ g3,
    float* __restrict__ outp)
{
  const int tid = threadIdx.x;
  const int b = blockIdx.x >> 7;
  const int l0 = (blockIdx.x & 127) << 5;
  __shared__ float xs[256][36];
  __shared__ float hsm[64][36];
  __shared__ float cgs[256];
  const size_t rowbase = ((size_t)b << 20) + (size_t)l0;

  {
    const int cw = tid >> 3, g = (tid & 7) << 2;
#pragma unroll
    for (int pass = 0; pass < 16; ++pass) {
      const int c = (pass << 4) + cw;
      const size_t off = rowbase + ((size_t)c << 12) + g;
      const float4 vo = *(const float4*)(xo1 + off);
      const float4 vq = *(const float4*)(xc + off);
      float4 v;
      v.x = vo.x + vq.x; v.y = vo.y + vq.y; v.z = vo.z + vq.z; v.w = vo.w + vq.w;
      *(float4*)&xs[c][g] = v;
    }
    cgs[tid] = c2[tid] + g3[(b << 8) + tid];
    cgs[tid + 128] = c2[tid + 128] + g3[(b << 8) + tid + 128];
  }
  __syncthreads();

  {
    const int ti = tid >> 3, tt4 = (tid & 7) << 2;
    float acc[4][4] = {};
    const float* wp = W1t + (ti << 2);
#pragma unroll 4
    for (int c = 0; c < 256; ++c) {
      const float4 wv = *(const float4*)(wp + (c << 6));
      const float4 xv = *(const float4*)&xs[c][tt4];
      const float wv4[4] = {wv.x, wv.y, wv.z, wv.w};
      const float xv4[4] = {xv.x, xv.y, xv.z, xv.w};
#pragma unroll
      for (int a = 0; a < 4; ++a)
#pragma unroll
        for (int j = 0; j < 4; ++j)
          acc[a][j] = fmaf(wv4[a], xv4[j], acc[a][j]);
    }
#pragma unroll
    for (int a = 0; a < 4; ++a) {
      const float cv = c1[(ti << 2) + a];
      float4 h;
      h.x = fmaxf(acc[a][0] + cv, 0.0f);
      h.y = fmaxf(acc[a][1] + cv, 0.0f);
      h.z = fmaxf(acc[a][2] + cv, 0.0f);
      h.w = fmaxf(acc[a][3] + cv, 0.0f);
      *(float4*)&hsm[(ti << 2) + a][tt4] = h;
    }
  }
  __syncthreads();

  {
    const int cg = tid >> 2, tg8 = (tid & 3) << 3;
    float acc2[8][8] = {};
#pragma unroll 2
    for (int i = 0; i < 64; ++i) {
      const float4 h0 = *(const float4*)&hsm[i][tg8];
      const float4 h1 = *(const float4*)&hsm[i][tg8 + 4];
      const float* w2p = W2t + (i << 8) + (cg << 3);
      const float4 w0 = *(const float4*)(w2p);
      const float4 w1v = *(const float4*)(w2p + 4);
      const float hh[8] = {h0.x, h0.y, h0.z, h0.w, h1.x, h1.y, h1.z, h1.w};
      const float ww[8] = {w0.x, w0.y, w0.z, w0.w, w1v.x, w1v.y, w1v.z, w1v.w};
#pragma unroll
      for (int a = 0; a < 8; ++a)
#pragma unroll
        for (int j = 0; j < 8; ++j)
          acc2[a][j] = fmaf(ww[a], hh[j], acc2[a][j]);
    }

#pragma unroll
    for (int a = 0; a < 8; ++a) {
      const int cc = (cg << 3) + a;
      const float cgv = cgs[cc];
      const size_t off = rowbase + ((size_t)cc << 12) + tg8;
      const float4 q0 = *(const float4*)(xc + off);
      const float4 q1 = *(const float4*)(xc + off + 4);
      const float4 p0 = *(const float4*)(pbuf + off);
      const float4 p1 = *(const float4*)(pbuf + off + 4);
      const float4 s0 = *(const float4*)&xs[cc][tg8];
      const float4 s1 = *(const float4*)&xs[cc][tg8 + 4];
      const float qv[8] = {q0.x, q0.y, q0.z, q0.w, q1.x, q1.y, q1.z, q1.w};
      const float pv[8] = {p0.x, p0.y, p0.z, p0.w, p1.x, p1.y, p1.z, p1.w};
      const float sv[8] = {s0.x, s0.y, s0.z, s0.w, s1.x, s1.y, s1.z, s1.w};
      float ov[8];
#pragma unroll
      for (int j = 0; j < 8; ++j) {
        const float w2s = 1.0f / (1.0f + __expf(-(acc2[a][j] + cgv)));
        const float xo = sv[j] - qv[j];          // xo1
        ov[j] = 0.5f * xo * (1.0f + w2s) + pv[j];
      }
      float4 o0 = {ov[0], ov[1], ov[2], ov[3]}, o1 = {ov[4], ov[5], ov[6], ov[7]};
      *(float4*)(outp + off) = o0;
      *(float4*)(outp + off + 4) = o1;
    }
  }
}

extern "C" void kernel_launch(void* const* d_in, const int* in_sizes, int n_in,
                              void* d_out, int out_size, void* d_ws, size_t ws_size,
                              hipStream_t stream) {
  const float* xa = (const float*)d_in[0];
  const float* xb = (const float*)d_in[1];
  const float* xc = (const float*)d_in[2];
  const float* w1 = (const float*)d_in[3];
  const float* b1 = (const float*)d_in[4];
  const float* bn1g = (const float*)d_in[5];
  const float* bn1b = (const float*)d_in[6];
  const float* bn1m = (const float*)d_in[7];
  const float* bn1v = (const float*)d_in[8];
  const float* w2 = (const float*)d_in[9];
  const float* b2 = (const float*)d_in[10];
  const float* bn2g = (const float*)d_in[11];
  const float* bn2b = (const float*)d_in[12];
  const float* bn2m = (const float*)d_in[13];
  const float* bn2v = (const float*)d_in[14];
  float* ws = (float*)d_ws;
  float* outp = (float*)d_out;

  float* W1t0 = ws + OFF_W1T0;
  float* W2t0 = ws + OFF_W2T0;
  float* W1t2 = ws + OFF_W1T2;
  float* W2t2 = ws + OFF_W2T2;
  float* c1_0 = ws + OFF_C1_0;
  float* c2_0 = ws + OFF_C2_0;
  float* c1_2 = ws + OFF_C1_2;
  float* c2_2 = ws + OFF_C2_2;
  float* mean_ab = ws + OFF_MEANAB;
  float* sum_abc = ws + OFF_SUMABC;
  float* g1 = ws + OFF_G1;
  float* g3 = ws + OFF_G3;
  float* xo1 = ws + OFF_XO1;
  float* pbuf = ws + OFF_P;

  // 1) fold BN into weights; zero the round-2 mean accumulator
  k_prep<<<291, 256, 0, stream>>>(w1, b1, bn1g, bn1b, bn1m, bn1v,
                                  w2, b2, bn2g, bn2b, bn2m, bn2v, ws);
  // 2) mean over L of x_a+x_b  (one block per (b,c))
  k_mean_ab<<<8192, 256, 0, stream>>>(xa, xb, mean_ab);
  // 3) global-pool branch 1
  k_gatt<<<32, 256, 0, stream>>>(1, mean_ab, 1.0f,
                                 w1, b1, bn1g, bn1b, bn1m, bn1v,
                                 w2, b2, bn2g, bn2b, bn2m, bn2v, g1);
  // 4) local branch 0 + blend -> xo1, p, sum_abc
  k_local1<<<4096, 128, 0, stream>>>(xa, xb, xc, W1t0, W2t0, c1_0, c2_0, g1,
                                     xo1, pbuf, sum_abc);
  // 5) global-pool branch 3 on mean(xo1 + x_c)
  k_gatt<<<32, 256, 0, stream>>>(3, sum_abc, 1.0f / 4096.0f,
                                 w1, b1, bn1g, bn1b, bn1m, bn1v,
                                 w2, b2, bn2g, bn2b, bn2m, bn2v, g3);
  // 6) local branch 2 + final combine -> out
  k_local2<<<4096, 128, 0, stream>>>(xo1, xc, pbuf, W1t2, W2t2, c1_2, c2_2, g3,
                                     outp);
}

// Round 2
// 827.565 us; speedup vs baseline: 1.2986x; 1.2986x over previous
//
#include <hip/hip_runtime.h>
#include <cstddef>

#define EPS_ 1e-5f

// Problem constants: B=32, C=256, L=4096, I=64
// x layout [B][C][L] row-major; elem (b,c,l) at (b*256+c)*4096 + l.

// ---- ws float offsets ----
// Folded weights: W1t[c][i] = s1[i]*w1[br][i][c]; W2t[i][c] = s2[c]*w2[br][c][i]
#define OFF_W1T0 0
#define OFF_W2T0 16384
#define OFF_W1T2 32768
#define OFF_W2T2 49152
#define OFF_C1_0 65536   // 64   c1 = bn1_b + s1*(b1 - bn1_m)
#define OFF_C2_0 65600   // 256
#define OFF_C1_2 65856   // 64
#define OFF_C2_2 65920   // 256
#define OFF_MEANAB 66176 // [32][256]
#define OFF_SUMABC 74368 // [32][256] (atomic accum, zeroed in prep)
#define OFF_G1 82560     // [32][256]
#define OFF_G3 90752     // [32][256]
#define OFF_XO1 131072   // [32][256][4096]
#define OFF_P 33685504   // [32][256][4096]  p = 0.5*(1-wei)*x_c
// total ws need: 67239936 floats = ~269 MB

// ============ prep: fold BN into weights, zero sum_abc ============
__global__ __launch_bounds__(256) void k_prep(
    const float* __restrict__ w1, const float* __restrict__ b1,
    const float* __restrict__ bn1g, const float* __restrict__ bn1b,
    const float* __restrict__ bn1m, const float* __restrict__ bn1v,
    const float* __restrict__ w2, const float* __restrict__ b2,
    const float* __restrict__ bn2g, const float* __restrict__ bn2b,
    const float* __restrict__ bn2m, const float* __restrict__ bn2v,
    float* __restrict__ ws)
{
  int idx = blockIdx.x * 256 + threadIdx.x;
  if (idx < 32768) {                       // W1t, branches 0 and 2
    int slot = idx >> 14, r = idx & 16383;
    int br = slot << 1;
    int c = r >> 6, i = r & 63;
    int gi = (br << 6) + i;
    float s1 = bn1g[gi] / sqrtf(bn1v[gi] + EPS_);
    ws[OFF_W1T0 + (slot << 15) + r] = w1[gi * 256 + c] * s1;
  } else if (idx < 65536) {                // W2t
    int j = idx - 32768;
    int slot = j >> 14, r = j & 16383;
    int br = slot << 1;
    int i = r >> 8, c = r & 255;
    int gc = (br << 8) + c;
    float s2 = bn2g[gc] / sqrtf(bn2v[gc] + EPS_);
    ws[OFF_W2T0 + (slot << 15) + r] = w2[gc * 64 + i] * s2;
  } else if (idx < 65664) {                // c1
    int j = idx - 65536;
    int slot = j >> 6, i = j & 63;
    int gi = ((slot << 1) << 6) + i;
    float s1 = bn1g[gi] / sqrtf(bn1v[gi] + EPS_);
    ws[OFF_C1_0 + slot * 320 + i] = bn1b[gi] + s1 * (b1[gi] - bn1m[gi]);
  } else if (idx < 66176) {                // c2
    int j = idx - 65664;
    int slot = j >> 8, c = j & 255;
    int gc = ((slot << 1) << 8) + c;
    float s2 = bn2g[gc] / sqrtf(bn2v[gc] + EPS_);
    ws[OFF_C2_0 + slot * 320 + c] = bn2b[gc] + s2 * (b2[gc] - bn2m[gc]);
  } else if (idx < 74368) {                // zero sum_abc
    ws[OFF_SUMABC + (idx - 66176)] = 0.0f;
  }
}

// ============ K1: mean over L of (x_a + x_b), one block per (b,c) ============
__global__ __launch_bounds__(256) void k_mean_ab(
    const float* __restrict__ xa, const float* __restrict__ xb,
    float* __restrict__ mean_ab)
{
  const int row = blockIdx.x;              // b*256 + c
  const size_t base4 = (size_t)row * 1024; // float4 units
  const float4* a4 = (const float4*)xa;
  const float4* b4 = (const float4*)xb;
  float s = 0.0f;
#pragma unroll
  for (int k = 0; k < 4; ++k) {
    float4 va = a4[base4 + k * 256 + threadIdx.x];
    float4 vb = b4[base4 + k * 256 + threadIdx.x];
    s += (va.x + vb.x) + (va.y + vb.y) + (va.z + vb.z) + (va.w + vb.w);
  }
#pragma unroll
  for (int m = 32; m; m >>= 1) s += __shfl_xor(s, m, 64);
  __shared__ float part[4];
  if ((threadIdx.x & 63) == 0) part[threadIdx.x >> 6] = s;
  __syncthreads();
  if (threadIdx.x == 0)
    mean_ab[row] = (part[0] + part[1] + part[2] + part[3]) * (1.0f / 4096.0f);
}

// ============ global-pool attention branch (br = 1 or 3), one block per b ===
__global__ __launch_bounds__(256) void k_gatt(
    int br, const float* __restrict__ vin, float scale,
    const float* __restrict__ w1, const float* __restrict__ b1,
    const float* __restrict__ bn1g, const float* __restrict__ bn1b,
    const float* __restrict__ bn1m, const float* __restrict__ bn1v,
    const float* __restrict__ w2, const float* __restrict__ b2,
    const float* __restrict__ bn2g, const float* __restrict__ bn2b,
    const float* __restrict__ bn2m, const float* __restrict__ bn2v,
    float* __restrict__ gout)
{
  const int b = blockIdx.x, tid = threadIdx.x;
  __shared__ float xs[256];
  __shared__ float as[64];
  xs[tid] = vin[(b << 8) + tid] * scale;
  __syncthreads();
  if (tid < 64) {
    const int gi = (br << 6) + tid;
    const float* wr = w1 + gi * 256;
    float acc = 0.0f;
#pragma unroll 8
    for (int c = 0; c < 256; ++c) acc = fmaf(wr[c], xs[c], acc);
    float s1 = bn1g[gi] / sqrtf(bn1v[gi] + EPS_);
    float h = s1 * (acc + b1[gi] - bn1m[gi]) + bn1b[gi];
    as[tid] = fmaxf(h, 0.0f);
  }
  __syncthreads();
  const int gc = (br << 8) + tid;
  const float* wr2 = w2 + gc * 64;
  float acc = 0.0f;
#pragma unroll 8
  for (int i = 0; i < 64; ++i) acc = fmaf(wr2[i], as[i], acc);
  float s2 = bn2g[gc] / sqrtf(bn2v[gc] + EPS_);
  gout[(b << 8) + tid] = s2 * (acc + b2[gc] - bn2m[gc]) + bn2b[gc];
}

// ============ K2: local attn branch 0 + first blend ============
// 2048 blocks x 256 threads; block = (b, 64-position l-tile).
// K=256 staged in 4 chunks of 64c x 64l (16 KB LDS, aliased with h-buffer).
// Writes xo1, p = 0.5*(1-wei)*x_c; atomically accumulates sum_l(xo1 + x_c).
__global__ __launch_bounds__(256, 4) void k_local1(
    const float* __restrict__ xa, const float* __restrict__ xb,
    const float* __restrict__ xc,
    const float* __restrict__ W1t, const float* __restrict__ W2t,
    const float* __restrict__ c1, const float* __restrict__ c2,
    const float* __restrict__ g1,
    float* __restrict__ xo1, float* __restrict__ pbuf,
    float* __restrict__ sumabc)
{
  const int tid = threadIdx.x;
  const int b = blockIdx.x >> 6;
  const int l0tile = (blockIdx.x & 63) << 6;   // 64 positions
  __shared__ float xs[64][64];                 // chunk buffer, later h-buffer
  __shared__ float cgs[256];                   // c2 + g1 row
  const size_t rowbase = ((size_t)b << 20) + (size_t)l0tile;

  cgs[tid] = c2[tid] + g1[(b << 8) + tid];

  // ---- layer 1: h[64 i][64 l], K chunked by 64 ----
  const int ti = tid >> 4, i0 = ti << 2;       // i block (0..60)
  const int lt = tid & 15, l0 = lt << 2;       // l block (0..60)
  float acc[4][4] = {};
  const int srow = tid >> 4;                   // staging row within 16-row pass
  const int scol = (tid & 15) << 2;

  for (int kb = 0; kb < 4; ++kb) {
    __syncthreads();                            // protect xs from prev readers
#pragma unroll
    for (int pass = 0; pass < 4; ++pass) {
      const int r = (pass << 4) + srow;         // 0..63 within chunk
      const size_t off = rowbase + (((size_t)(kb << 6) + r) << 12) + scol;
      const float4 va = *(const float4*)(xa + off);
      const float4 vb = *(const float4*)(xb + off);
      float4 v;
      v.x = va.x + vb.x; v.y = va.y + vb.y; v.z = va.z + vb.z; v.w = va.w + vb.w;
      *(float4*)&xs[r][scol] = v;
    }
    __syncthreads();

    const float* wp = W1t + ((kb << 6) << 6) + i0;
#pragma unroll 4
    for (int c = 0; c < 64; ++c) {
      const float4 wv = *(const float4*)(wp + (c << 6));
      const float4 xv = *(const float4*)&xs[c][l0];
      const float wv4[4] = {wv.x, wv.y, wv.z, wv.w};
      const float xv4[4] = {xv.x, xv.y, xv.z, xv.w};
#pragma unroll
      for (int a = 0; a < 4; ++a)
#pragma unroll
        for (int j = 0; j < 4; ++j)
          acc[a][j] = fmaf(wv4[a], xv4[j], acc[a][j]);
    }
  }

  // ---- bias + ReLU, h into xs (aliased) ----
  __syncthreads();
#pragma unroll
  for (int a = 0; a < 4; ++a) {
    const float cv = c1[i0 + a];
    float4 h;
    h.x = fmaxf(acc[a][0] + cv, 0.0f);
    h.y = fmaxf(acc[a][1] + cv, 0.0f);
    h.z = fmaxf(acc[a][2] + cv, 0.0f);
    h.w = fmaxf(acc[a][3] + cv, 0.0f);
    *(float4*)&xs[i0 + a][l0] = h;
  }
  __syncthreads();

  // ---- layer 2 (8c x 8l micro) + sigmoid + blend ----
  const int cg = tid >> 3, c0 = cg << 3;       // 8 channels
  const int lt2 = tid & 7, l0b = lt2 << 3;     // 8 positions
  float acc2[8][8] = {};
#pragma unroll 2
  for (int i = 0; i < 64; ++i) {
    const float4 h0 = *(const float4*)&xs[i][l0b];
    const float4 h1 = *(const float4*)&xs[i][l0b + 4];
    const float* w2p = W2t + (i << 8) + c0;
    const float4 w0 = *(const float4*)(w2p);
    const float4 w1v = *(const float4*)(w2p + 4);
    const float hh[8] = {h0.x, h0.y, h0.z, h0.w, h1.x, h1.y, h1.z, h1.w};
    const float ww[8] = {w0.x, w0.y, w0.z, w0.w, w1v.x, w1v.y, w1v.z, w1v.w};
#pragma unroll
    for (int a = 0; a < 8; ++a)
#pragma unroll
      for (int j = 0; j < 8; ++j)
        acc2[a][j] = fmaf(ww[a], hh[j], acc2[a][j]);
  }

#pragma unroll
  for (int a = 0; a < 8; ++a) {
    const int cc = c0 + a;
    const float cgv = cgs[cc];
    const size_t off = rowbase + ((size_t)cc << 12) + l0b;
    const float4 a0 = *(const float4*)(xa + off);
    const float4 a1 = *(const float4*)(xa + off + 4);
    const float4 b0 = *(const float4*)(xb + off);
    const float4 b1v = *(const float4*)(xb + off + 4);
    const float4 q0 = *(const float4*)(xc + off);
    const float4 q1 = *(const float4*)(xc + off + 4);
    const float av[8] = {a0.x, a0.y, a0.z, a0.w, a1.x, a1.y, a1.z, a1.w};
    const float bv[8] = {b0.x, b0.y, b0.z, b0.w, b1v.x, b1v.y, b1v.z, b1v.w};
    const float qv[8] = {q0.x, q0.y, q0.z, q0.w, q1.x, q1.y, q1.z, q1.w};
    float ov[8], pv[8], sab = 0.0f;
#pragma unroll
    for (int j = 0; j < 8; ++j) {
      const float w = 1.0f / (1.0f + __expf(-(acc2[a][j] + cgv)));
      const float xo = av[j] * w + bv[j] * (1.0f - w);
      ov[j] = xo;
      pv[j] = 0.5f * (1.0f - w) * qv[j];
      sab += xo + qv[j];
    }
    float4 o0 = {ov[0], ov[1], ov[2], ov[3]}, o1 = {ov[4], ov[5], ov[6], ov[7]};
    float4 p0 = {pv[0], pv[1], pv[2], pv[3]}, p1 = {pv[4], pv[5], pv[6], pv[7]};
    *(float4*)(xo1 + off) = o0;  *(float4*)(xo1 + off + 4) = o1;
    *(float4*)(pbuf + off) = p0; *(float4*)(pbuf + off + 4) = p1;
    sab += __shfl_xor(sab, 1, 64);
    sab += __shfl_xor(sab, 2, 64);
    sab += __shfl_xor(sab, 4, 64);
    if (lt2 == 0) atomicAdd(&sumabc[(b << 8) + cc], sab);
  }
}

// ============ K4: local attn branch 2 + final combine ============
// out = 0.5*xo1*(1+wei2) + p
__global__ __launch_bounds__(256, 4) void k_local2(
    const float* __restrict__ xo1, const float* __restrict__ xc,
    const float* __restrict__ pbuf,
    const float* __restrict__ W1t, const float* __restrict__ W2t,
    const float* __restrict__ c1, const float* __restrict__ c2,
    const float* __restrict__ g3,
    float* __restrict__ outp)
{
  const int tid = threadIdx.x;
  const int b = blockIdx.x >> 6;
  const int l0tile = (blockIdx.x & 63) << 6;
  __shared__ float xs[64][64];
  __shared__ float cgs[256];
  const size_t rowbase = ((size_t)b << 20) + (size_t)l0tile;

  cgs[tid] = c2[tid] + g3[(b << 8) + tid];

  const int ti = tid >> 4, i0 = ti << 2;
  const int lt = tid & 15, l0 = lt << 2;
  float acc[4][4] = {};
  const int srow = tid >> 4;
  const int scol = (tid & 15) << 2;

  for (int kb = 0; kb < 4; ++kb) {
    __syncthreads();
#pragma unroll
    for (int pass = 0; pass < 4; ++pass) {
      const int r = (pass << 4) + srow;
      const size_t off = rowbase + (((size_t)(kb << 6) + r) << 12) + scol;
      const float4 vo = *(const float4*)(xo1 + off);
      const float4 vq = *(const float4*)(xc + off);
      float4 v;
      v.x = vo.x + vq.x; v.y = vo.y + vq.y; v.z = vo.z + vq.z; v.w = vo.w + vq.w;
      *(float4*)&xs[r][scol] = v;
    }
    __syncthreads();

    const float* wp = W1t + ((kb << 6) << 6) + i0;
#pragma unroll 4
    for (int c = 0; c < 64; ++c) {
      const float4 wv = *(const float4*)(wp + (c << 6));
      const float4 xv = *(const float4*)&xs[c][l0];
      const float wv4[4] = {wv.x, wv.y, wv.z, wv.w};
      const float xv4[4] = {xv.x, xv.y, xv.z, xv.w};
#pragma unroll
      for (int a = 0; a < 4; ++a)
#pragma unroll
        for (int j = 0; j < 4; ++j)
          acc[a][j] = fmaf(wv4[a], xv4[j], acc[a][j]);
    }
  }

  __syncthreads();
#pragma unroll
  for (int a = 0; a < 4; ++a) {
    const float cv = c1[i0 + a];
    float4 h;
    h.x = fmaxf(acc[a][0] + cv, 0.0f);
    h.y = fmaxf(acc[a][1] + cv, 0.0f);
    h.z = fmaxf(acc[a][2] + cv, 0.0f);
    h.w = fmaxf(acc[a][3] + cv, 0.0f);
    *(float4*)&xs[i0 + a][l0] = h;
  }
  __syncthreads();

  const int cg = tid >> 3, c0 = cg << 3;
  const int lt2 = tid & 7, l0b = lt2 << 3;
  float acc2[8][8] = {};
#pragma unroll 2
  for (int i = 0; i < 64; ++i) {
    const float4 h0 = *(const float4*)&xs[i][l0b];
    const float4 h1 = *(const float4*)&xs[i][l0b + 4];
    const float* w2p = W2t + (i << 8) + c0;
    const float4 w0 = *(const float4*)(w2p);
    const float4 w1v = *(const float4*)(w2p + 4);
    const float hh[8] = {h0.x, h0.y, h0.z, h0.w, h1.x, h1.y, h1.z, h1.w};
    const float ww[8] = {w0.x, w0.y, w0.z, w0.w, w1v.x, w1v.y, w1v.z, w1v.w};
#pragma unroll
    for (int a = 0; a < 8; ++a)
#pragma unroll
      for (int j = 0; j < 8; ++j)
        acc2[a][j] = fmaf(ww[a], hh[j], acc2[a][j]);
  }

#pragma unroll
  for (int a = 0; a < 8; ++a) {
    const int cc = c0 + a;
    const float cgv = cgs[cc];
    const size_t off = rowbase + ((size_t)cc << 12) + l0b;
    const float4 o0g = *(const float4*)(xo1 + off);
    const float4 o1g = *(const float4*)(xo1 + off + 4);
    const float4 p0 = *(const float4*)(pbuf + off);
    const float4 p1 = *(const float4*)(pbuf + off + 4);
    const float xov[8] = {o0g.x, o0g.y, o0g.z, o0g.w, o1g.x, o1g.y, o1g.z, o1g.w};
    const float pv[8] = {p0.x, p0.y, p0.z, p0.w, p1.x, p1.y, p1.z, p1.w};
    float ov[8];
#pragma unroll
    for (int j = 0; j < 8; ++j) {
      const float w2s = 1.0f / (1.0f + __expf(-(acc2[a][j] + cgv)));
      ov[j] = 0.5f * xov[j] * (1.0f + w2s) + pv[j];
    }
    float4 r0 = {ov[0], ov[1], ov[2], ov[3]}, r1 = {ov[4], ov[5], ov[6], ov[7]};
    *(float4*)(outp + off) = r0;
    *(float4*)(outp + off + 4) = r1;
  }
}

extern "C" void kernel_launch(void* const* d_in, const int* in_sizes, int n_in,
                              void* d_out, int out_size, void* d_ws, size_t ws_size,
                              hipStream_t stream) {
  const float* xa = (const float*)d_in[0];
  const float* xb = (const float*)d_in[1];
  const float* xc = (const float*)d_in[2];
  const float* w1 = (const float*)d_in[3];
  const float* b1 = (const float*)d_in[4];
  const float* bn1g = (const float*)d_in[5];
  const float* bn1b = (const float*)d_in[6];
  const float* bn1m = (const float*)d_in[7];
  const float* bn1v = (const float*)d_in[8];
  const float* w2 = (const float*)d_in[9];
  const float* b2 = (const float*)d_in[10];
  const float* bn2g = (const float*)d_in[11];
  const float* bn2b = (const float*)d_in[12];
  const float* bn2m = (const float*)d_in[13];
  const float* bn2v = (const float*)d_in[14];
  float* ws = (float*)d_ws;
  float* outp = (float*)d_out;

  float* W1t0 = ws + OFF_W1T0;
  float* W2t0 = ws + OFF_W2T0;
  float* W1t2 = ws + OFF_W1T2;
  float* W2t2 = ws + OFF_W2T2;
  float* c1_0 = ws + OFF_C1_0;
  float* c2_0 = ws + OFF_C2_0;
  float* c1_2 = ws + OFF_C1_2;
  float* c2_2 = ws + OFF_C2_2;
  float* mean_ab = ws + OFF_MEANAB;
  float* sum_abc = ws + OFF_SUMABC;
  float* g1 = ws + OFF_G1;
  float* g3 = ws + OFF_G3;
  float* xo1 = ws + OFF_XO1;
  float* pbuf = ws + OFF_P;

  // 1) fold BN into weights; zero the round-2 mean accumulator
  k_prep<<<291, 256, 0, stream>>>(w1, b1, bn1g, bn1b, bn1m, bn1v,
                                  w2, b2, bn2g, bn2b, bn2m, bn2v, ws);
  // 2) mean over L of x_a+x_b  (one block per (b,c))
  k_mean_ab<<<8192, 256, 0, stream>>>(xa, xb, mean_ab);
  // 3) global-pool branch 1
  k_gatt<<<32, 256, 0, stream>>>(1, mean_ab, 1.0f,
                                 w1, b1, bn1g, bn1b, bn1m, bn1v,
                                 w2, b2, bn2g, bn2b, bn2m, bn2v, g1);
  // 4) local branch 0 + blend -> xo1, p, sum_abc
  k_local1<<<2048, 256, 0, stream>>>(xa, xb, xc, W1t0, W2t0, c1_0, c2_0, g1,
                                     xo1, pbuf, sum_abc);
  // 5) global-pool branch 3 on mean(xo1 + x_c)
  k_gatt<<<32, 256, 0, stream>>>(3, sum_abc, 1.0f / 4096.0f,
                                 w1, b1, bn1g, bn1b, bn1m, bn1v,
                                 w2, b2, bn2g, bn2b, bn2m, bn2v, g3);
  // 6) local branch 2 + final combine -> out
  k_local2<<<2048, 256, 0, stream>>>(xo1, xc, pbuf, W1t2, W2t2, c1_2, c2_2, g3,
                                     outp);
}